// Round 2
// baseline (9181.978 us; speedup 1.0000x reference)
//
#include <hip/hip_runtime.h>
#include <math.h>

// Problem constants
#define EMBD 400
#define HIDD 300
#define KEYD 128
#define VALD 128
#define NVOC 33
#define TT 256
#define BB 256
#define SS 512
#define WIH_LD 528          // EMB+VAL
#define GDIM 1200           // 4*HID
#define KTOT 428            // ctx(128)+h(300)
#define KPAD 432            // padded to multiple of 16 for clean unroll
#define NBLK 256            // one block per batch row -> all 256 CUs

typedef unsigned int u32x4 __attribute__((ext_vector_type(4)));
typedef unsigned int u32x2 __attribute__((ext_vector_type(2)));

__device__ __forceinline__ float bflo(unsigned int u) {
    return __uint_as_float(u << 16);
}
__device__ __forceinline__ float bfhi(unsigned int u) {
    return __uint_as_float(u & 0xffff0000u);
}
__device__ __forceinline__ unsigned short f2bf(float x) {   // RNE, no NaN inputs
    unsigned int u = __float_as_uint(x);
    return (unsigned short)((u + 0x7fffu + ((u >> 16) & 1u)) >> 16);
}
__device__ __forceinline__ float sigmoidf_(float x) {
    return 1.f / (1.f + __expf(-x));
}
__device__ __forceinline__ float tanh_f(float x) {
    float ax = fabsf(x);
    if (ax > 15.f) return x > 0.f ? 1.f : -1.f;
    float e = __expf(2.f * x);
    return (e - 1.f) / (e + 1.f);
}
__device__ __forceinline__ float4 add4(float4 a, float4 b) {
    return make_float4(a.x + b.x, a.y + b.y, a.z + b.z, a.w + b.w);
}

// ---------------- Precompute: E2[v][j] = b_ih[j]+b_hh[j]+emb[v]·W_ih[j][:400]
__global__ __launch_bounds__(256) void p_e2(
    const float* __restrict__ emb, const float* __restrict__ Wih,
    const float* __restrict__ bih, const float* __restrict__ bhh,
    float* __restrict__ E2)
{
    __shared__ float es[EMBD];
    const int v = blockIdx.x;
    for (int i = threadIdx.x; i < EMBD; i += 256) es[i] = emb[v * EMBD + i];
    __syncthreads();
    for (int j = threadIdx.x; j < GDIM; j += 256) {
        const float* wr = &Wih[(size_t)j * WIH_LD];
        float s0 = 0.f, s1 = 0.f, s2 = 0.f, s3 = 0.f;
        for (int e = 0; e < EMBD; e += 4) {
            s0 += es[e]     * wr[e];
            s1 += es[e + 1] * wr[e + 1];
            s2 += es[e + 2] * wr[e + 2];
            s3 += es[e + 3] * wr[e + 3];
        }
        E2[v * GDIM + j] = bih[j] + bhh[j] + ((s0 + s1) + (s2 + s3));
    }
}

// ---------------- Precompute: Wtb (bf16, fused+transposed, K padded) + phi_wT
__global__ __launch_bounds__(256) void p_wt(
    const float* __restrict__ Wih, const float* __restrict__ Whh,
    const float* __restrict__ phi_w,
    unsigned short* __restrict__ Wtb, float* __restrict__ phi_wT)
{
    const int stride = gridDim.x * 256;
    for (int i = blockIdx.x * 256 + threadIdx.x; i < KPAD * GDIM; i += stride) {
        int k = i / GDIM, j = i - k * GDIM;
        float v = 0.f;
        if (k < KEYD)      v = Wih[(size_t)j * WIH_LD + EMBD + k];
        else if (k < KTOT) v = Whh[(size_t)j * HIDD + (k - KEYD)];
        Wtb[i] = f2bf(v);
    }
    for (int i = blockIdx.x * 256 + threadIdx.x; i < KEYD * HIDD; i += stride) {
        int k = i / HIDD, ii = i - k * HIDD;   // phi_w[k][ii]
        phi_wT[ii * KEYD + k] = phi_w[i];
    }
}

// ---------------- Precompute: KV -> bf16, transposed to [b][s][dim]
__global__ __launch_bounds__(1024) void p_kv(
    const float* __restrict__ keys, const float* __restrict__ values,
    unsigned short* __restrict__ kbf, unsigned short* __restrict__ vbf)
{
    size_t i = (size_t)blockIdx.x * 1024 + threadIdx.x;  // S*B*K total exactly
    int s = (int)(i >> 15);
    int r = (int)(i & 32767);
    int b = r >> 7, k = r & 127;
    size_t d = (((size_t)b * SS + s) << 7) + k;
    kbf[d] = f2bf(keys[i]);
    vbf[d] = f2bf(values[i]);
}

// ---------------- gates GEMM chunk: j-quad q, k4 range [k4base, k4base+NK4)
// Wtb is [k][j] bf16; u32x2 index = k*300 + q covers j = 4q..4q+3.
template<int NK4>
__device__ __forceinline__ void gemm_chunk(
    const unsigned short* __restrict__ Wtb, const float* __restrict__ xin,
    int q, int k4base,
    float& a0, float& a1, float& a2, float& a3)
{
    const u32x2* Wp = reinterpret_cast<const u32x2*>(Wtb) + q;
    #pragma unroll 4
    for (int k4 = 0; k4 < NK4; ++k4) {
        const int k = (k4base + k4) * 4;
        float4 x = *reinterpret_cast<const float4*>(&xin[k]);  // LDS broadcast
        const size_t kk = (size_t)k * 300;
        u32x2 w0 = Wp[kk];
        u32x2 w1 = Wp[kk + 300];
        u32x2 w2 = Wp[kk + 600];
        u32x2 w3 = Wp[kk + 900];
        a0 += x.x * bflo(w0.x) + x.y * bflo(w1.x)
            + x.z * bflo(w2.x) + x.w * bflo(w3.x);
        a1 += x.x * bfhi(w0.x) + x.y * bfhi(w1.x)
            + x.z * bfhi(w2.x) + x.w * bfhi(w3.x);
        a2 += x.x * bflo(w0.y) + x.y * bflo(w1.y)
            + x.z * bflo(w2.y) + x.w * bflo(w3.y);
        a3 += x.x * bfhi(w0.y) + x.y * bfhi(w1.y)
            + x.z * bfhi(w2.y) + x.w * bfhi(w3.y);
    }
}

// ---------------- q partials: 512 threads = 128 k x 4 i-slices of 75
__device__ __forceinline__ void qpart_fn(
    int tid, const float* __restrict__ h_s, const float* __restrict__ phi_wT,
    float (*qp)[KEYD])
{
    const int k = tid & 127, sl = tid >> 7;
    const int i0 = sl * 75;
    float acc = 0.f;
    #pragma unroll 15
    for (int i = i0; i < i0 + 75; ++i)
        acc += h_s[i] * phi_wT[i * KEYD + k];
    qp[sl][k] = acc;
}

// ---------------- energy: 512 threads; folds q = phi_b + sum(qp) on the fly
template<int KVBF>
__device__ __forceinline__ void energy_fn(
    int tid, int b, const unsigned short* __restrict__ kbf,
    const float* __restrict__ keysf, const float (*qp)[KEYD],
    const float* __restrict__ phi_b, float* __restrict__ att)
{
    const int l16 = tid & 15, sg = tid >> 4;   // sg 0..31
    const int ia = l16 * 2, ib = ia + 1;
    const float4* pb4 = reinterpret_cast<const float4*>(phi_b);
    const float4* q0 = reinterpret_cast<const float4*>(qp[0]);
    const float4* q1 = reinterpret_cast<const float4*>(qp[1]);
    const float4* q2 = reinterpret_cast<const float4*>(qp[2]);
    const float4* q3 = reinterpret_cast<const float4*>(qp[3]);
    const float4 qa = add4(add4(pb4[ia], q0[ia]), add4(add4(q1[ia], q2[ia]), q3[ia]));
    const float4 qb = add4(add4(pb4[ib], q0[ib]), add4(add4(q1[ib], q2[ib]), q3[ib]));
    if (KVBF) {
        const unsigned short* krow = kbf + ((size_t)b * SS) * KEYD;
        #pragma unroll 4
        for (int p = 0; p < 16; ++p) {
            int s = p * 32 + sg;
            const u32x4* kp = reinterpret_cast<const u32x4*>(
                krow + (size_t)s * KEYD);
            u32x4 w = __builtin_nontemporal_load(kp + l16);
            float e = bflo(w.x) * qa.x + bfhi(w.x) * qa.y
                    + bflo(w.y) * qa.z + bfhi(w.y) * qa.w
                    + bflo(w.z) * qb.x + bfhi(w.z) * qb.y
                    + bflo(w.w) * qb.z + bfhi(w.w) * qb.w;
            e += __shfl_xor(e, 1);
            e += __shfl_xor(e, 2);
            e += __shfl_xor(e, 4);
            e += __shfl_xor(e, 8);
            if (l16 == 0) att[s] = e;
        }
    } else {
        #pragma unroll 4
        for (int p = 0; p < 16; ++p) {
            int s = p * 32 + sg;
            const float4* kp = reinterpret_cast<const float4*>(
                &keysf[((size_t)s * BB + b) * KEYD]);
            float4 ka = kp[l16 * 2], kb = kp[l16 * 2 + 1];
            float e = ka.x * qa.x + ka.y * qa.y + ka.z * qa.z + ka.w * qa.w
                    + kb.x * qb.x + kb.y * qb.y + kb.z * qb.z + kb.w * qb.w;
            e += __shfl_xor(e, 1);
            e += __shfl_xor(e, 2);
            e += __shfl_xor(e, 4);
            e += __shfl_xor(e, 8);
            if (l16 == 0) att[s] = e;
        }
    }
}

// ---------------- softmax over 512 energies by ONE wave (8 per lane)
__device__ __forceinline__ void softmax_fn(int tid, float* __restrict__ att)
{
    float4* a4 = reinterpret_cast<float4*>(att);
    float4 e0 = a4[tid * 2], e1 = a4[tid * 2 + 1];
    float m = fmaxf(fmaxf(fmaxf(e0.x, e0.y), fmaxf(e0.z, e0.w)),
                    fmaxf(fmaxf(e1.x, e1.y), fmaxf(e1.z, e1.w)));
    #pragma unroll
    for (int off = 32; off; off >>= 1) m = fmaxf(m, __shfl_xor(m, off));
    float p0 = __expf(e0.x - m), p1 = __expf(e0.y - m);
    float p2 = __expf(e0.z - m), p3 = __expf(e0.w - m);
    float p4 = __expf(e1.x - m), p5 = __expf(e1.y - m);
    float p6 = __expf(e1.z - m), p7 = __expf(e1.w - m);
    float ss = ((p0 + p1) + (p2 + p3)) + ((p4 + p5) + (p6 + p7));
    #pragma unroll
    for (int off = 32; off; off >>= 1) ss += __shfl_xor(ss, off);
    float inv = 1.f / ss;
    a4[tid * 2]     = make_float4(p0 * inv, p1 * inv, p2 * inv, p3 * inv);
    a4[tid * 2 + 1] = make_float4(p4 * inv, p5 * inv, p6 * inv, p7 * inv);
}

// ---------------- ctx partials: all 1024 threads; 32 s-groups x 16 s
template<int KVBF>
__device__ __forceinline__ void ctx_fn(
    int tid, int b, const unsigned short* __restrict__ vbf,
    const float* __restrict__ valuesf, const float* __restrict__ att,
    float (*cpart)[VALD])
{
    const int v4 = tid & 31, sg = tid >> 5;   // sg 0..31
    float4 a = make_float4(0.f, 0.f, 0.f, 0.f);
    if (KVBF) {
        const unsigned short* vrow = vbf + ((size_t)b * SS) * VALD;
        #pragma unroll 4
        for (int i = 0; i < 16; ++i) {
            int s = sg * 16 + i;
            const u32x2* vp = reinterpret_cast<const u32x2*>(
                vrow + (size_t)s * VALD);
            u32x2 w = __builtin_nontemporal_load(vp + v4);
            float wt = att[s];
            a.x += wt * bflo(w.x); a.y += wt * bfhi(w.x);
            a.z += wt * bflo(w.y); a.w += wt * bfhi(w.y);
        }
    } else {
        #pragma unroll 4
        for (int i = 0; i < 16; ++i) {
            int s = sg * 16 + i;
            float wt = att[s];
            const float4* vp = reinterpret_cast<const float4*>(
                &valuesf[((size_t)s * BB + b) * VALD]);
            float4 v = vp[v4];
            a.x += wt * v.x; a.y += wt * v.y;
            a.z += wt * v.z; a.w += wt * v.w;
        }
    }
    *reinterpret_cast<float4*>(&cpart[sg][v4 * 4]) = a;
}

__device__ __forceinline__ void reduce_fn(
    int tid, const float (*cpart)[VALD], float* __restrict__ ctx_s,
    float* __restrict__ xin)
{
    float s = 0.f;
    #pragma unroll
    for (int g = 0; g < 32; ++g) s += cpart[g][tid];
    ctx_s[tid] = s;
    xin[tid] = s;          // staged for Wctx GEMM
}

// ---------------- main body: one persistent block per batch row.
// Per step: P0 cell | P1 qpart || Whh1 || logits | P2 energy || Whh2
// | P3 softmax || Whh3 | P4 ctx(all) | P5 reduce | P6 Wctx.
template<int KVBF>
__device__ __forceinline__ void decoder_body(
    const int* __restrict__ input,
    const float* __restrict__ keysf, const float* __restrict__ valuesf,
    const unsigned short* __restrict__ kbf, const unsigned short* __restrict__ vbf,
    const float* __restrict__ phi_b, const float* __restrict__ h0,
    const float* __restrict__ c0, const float* __restrict__ projw,
    const float* __restrict__ projb, const float* __restrict__ E2,
    const unsigned short* __restrict__ Wtb, const float* __restrict__ phi_wT,
    float* __restrict__ out)
{
    const int tid = threadIdx.x;
    const int b = blockIdx.x;

    __shared__ float h_s[HIDD];
    __shared__ float c_s[HIDD];
    __shared__ float ctx_s[VALD];
    __shared__ __align__(16) float xin[KPAD];        // [ctx(128) | h(300) | pad]
    __shared__ __align__(16) float gp1[GDIM];        // Whh partial (full sums)
    __shared__ __align__(16) float gp2[3 * GDIM];    // Wctx partials (3 slices)
    __shared__ __align__(16) float att[SS];
    __shared__ __align__(16) float qp[4][KEYD];
    __shared__ __align__(16) float cpart[32][VALD];  // 16 KB
    __shared__ int xv_s;

    // ---- init
    for (int j = tid; j < HIDD; j += 1024) {
        float hv = h0[j];
        h_s[j] = hv;
        c_s[j] = c0[j];
        xin[VALD + j] = hv;
    }
    for (int j = tid; j < GDIM; j += 1024) gp1[j] = 0.f;
    if (tid < KPAD - KTOT) xin[KTOT + tid] = 0.f;
    if (tid == 0) xv_s = input[b];
    __syncthreads();

    // ---- prologue: ctx(-1) = attend(h0)
    if (tid < 512) qpart_fn(tid, h_s, phi_wT, qp);
    __syncthreads();
    if (tid < 512) energy_fn<KVBF>(tid, b, kbf, keysf, qp, phi_b, att);
    __syncthreads();
    if (tid < 64) softmax_fn(tid, att);
    __syncthreads();
    ctx_fn<KVBF>(tid, b, vbf, valuesf, att, cpart);
    __syncthreads();
    if (tid < VALD) reduce_fn(tid, cpart, ctx_s, xin);
    __syncthreads();

    // ---- prologue: full gates(0) -> gp2 (gp1 already zero)
    if (tid < 900) {
        const int c = tid / 300, q = tid - c * 300;
        float a0 = 0.f, a1 = 0.f, a2 = 0.f, a3 = 0.f;
        gemm_chunk<36>(Wtb, xin, q, c * 36, a0, a1, a2, a3);
        *reinterpret_cast<float4*>(gp2 + c * GDIM + 4 * q) =
            make_float4(a0, a1, a2, a3);
    }
    __syncthreads();

    #pragma unroll 1
    for (int t = 0; t < TT; ++t) {
        // ---- P0: cell update
        if (tid < HIDD) {
            const int j = tid;
            const float* e2r = E2 + (size_t)xv_s * GDIM;
            float s0 = gp1[j] + gp2[j] + gp2[GDIM + j]
                     + gp2[2 * GDIM + j] + e2r[j];
            float s1 = gp1[HIDD + j] + gp2[HIDD + j] + gp2[GDIM + HIDD + j]
                     + gp2[2 * GDIM + HIDD + j] + e2r[HIDD + j];
            float s2 = gp1[2 * HIDD + j] + gp2[2 * HIDD + j]
                     + gp2[GDIM + 2 * HIDD + j]
                     + gp2[2 * GDIM + 2 * HIDD + j] + e2r[2 * HIDD + j];
            float s3 = gp1[3 * HIDD + j] + gp2[3 * HIDD + j]
                     + gp2[GDIM + 3 * HIDD + j]
                     + gp2[2 * GDIM + 3 * HIDD + j] + e2r[3 * HIDD + j];
            float ig = sigmoidf_(s0);
            float fg = sigmoidf_(s1);
            float gt = tanh_f(s2);
            float og = sigmoidf_(s3);
            float cn = fg * c_s[j] + ig * gt;
            c_s[j] = cn;
            float hv = og * tanh_f(cn);
            h_s[j] = hv;
            xin[VALD + j] = hv;
        }
        __syncthreads();

        const bool last = (t == TT - 1);
        const int g = tid - 512;
        float a0 = 0.f, a1 = 0.f, a2 = 0.f, a3 = 0.f;  // Whh acc, lives P1..P3

        // ---- P1: qpart (A) || Whh chunk1 (G) || logits (G) || xv prefetch
        if (tid < 512) {
            if (!last) qpart_fn(tid, h_s, phi_wT, qp);
        } else if (g < 300) {
            if (!last) gemm_chunk<26>(Wtb, xin, g, 32, a0, a1, a2, a3);
        } else if (g < 432) {
            const int lg = g - 300;
            const int v = lg >> 2, l = lg & 3;       // 33 vocab x 4 lanes
            const float* pw = projw + (size_t)v * KTOT;
            float s = 0.f;
            #pragma unroll 8
            for (int k = l; k < KTOT; k += 4)
                s += pw[k] * ((k < HIDD) ? h_s[k] : ctx_s[k - HIDD]);
            s += __shfl_xor(s, 1);
            s += __shfl_xor(s, 2);
            if (l == 0)
                out[((size_t)t * BB + b) * NVOC + v] = s + projb[v];
        } else if (tid == 1023) {
            if (t + 1 < TT) xv_s = input[(t + 1) * BB + b];
        }
        __syncthreads();
        if (last) break;

        // ---- P2: energy (A) || Whh chunk2 (G)
        if (tid < 512) energy_fn<KVBF>(tid, b, kbf, keysf, qp, phi_b, att);
        else if (g < 300) gemm_chunk<26>(Wtb, xin, g, 58, a0, a1, a2, a3);
        __syncthreads();

        // ---- P3: softmax (wave 0) || Whh chunk3 + gp1 write (G)
        if (tid < 64) softmax_fn(tid, att);
        else if (g >= 0 && g < 300) {
            gemm_chunk<24>(Wtb, xin, g, 84, a0, a1, a2, a3);
            *reinterpret_cast<float4*>(gp1 + 4 * g) =
                make_float4(a0, a1, a2, a3);
        }
        __syncthreads();

        // ---- P4: ctx partials (all 1024)
        ctx_fn<KVBF>(tid, b, vbf, valuesf, att, cpart);
        __syncthreads();

        // ---- P5: ctx reduce -> ctx_s, xin
        if (tid < VALD) reduce_fn(tid, cpart, ctx_s, xin);
        __syncthreads();

        // ---- P6: Wctx GEMM (900 workers, 3 k-slices over ctx 128)
        if (tid < 900) {
            const int c = tid / 300, q = tid - c * 300;
            float b0 = 0.f, b1 = 0.f, b2 = 0.f, b3 = 0.f;
            if (c == 0)      gemm_chunk<11>(Wtb, xin, q, 0,  b0, b1, b2, b3);
            else if (c == 1) gemm_chunk<11>(Wtb, xin, q, 11, b0, b1, b2, b3);
            else             gemm_chunk<10>(Wtb, xin, q, 22, b0, b1, b2, b3);
            *reinterpret_cast<float4*>(gp2 + c * GDIM + 4 * q) =
                make_float4(b0, b1, b2, b3);
        }
        __syncthreads();
    }
}

__global__ void __launch_bounds__(1024, 4) decoder_bf(
    const int* input, const float* keysf, const float* valuesf,
    const unsigned short* kbf, const unsigned short* vbf,
    const float* phi_b, const float* h0, const float* c0,
    const float* projw, const float* projb, const float* E2,
    const unsigned short* Wtb, const float* phi_wT, float* out)
{
    decoder_body<1>(input, keysf, valuesf, kbf, vbf, phi_b, h0, c0,
                    projw, projb, E2, Wtb, phi_wT, out);
}

__global__ void __launch_bounds__(1024, 4) decoder_f32(
    const int* input, const float* keysf, const float* valuesf,
    const unsigned short* kbf, const unsigned short* vbf,
    const float* phi_b, const float* h0, const float* c0,
    const float* projw, const float* projb, const float* E2,
    const unsigned short* Wtb, const float* phi_wT, float* out)
{
    decoder_body<0>(input, keysf, valuesf, kbf, vbf, phi_b, h0, c0,
                    projw, projb, E2, Wtb, phi_wT, out);
}

// =====================================================================
extern "C" void kernel_launch(void* const* d_in, const int* in_sizes, int n_in,
                              void* d_out, int out_size, void* d_ws, size_t ws_size,
                              hipStream_t stream)
{
    const int*   input     = (const int*)  d_in[0];
    const float* keys      = (const float*)d_in[1];
    const float* values    = (const float*)d_in[2];
    const float* embedding = (const float*)d_in[3];
    const float* phi_w     = (const float*)d_in[4];
    const float* phi_b     = (const float*)d_in[5];
    const float* h0        = (const float*)d_in[6];
    const float* c0        = (const float*)d_in[7];
    const float* W_ih      = (const float*)d_in[8];
    const float* b_ih      = (const float*)d_in[9];
    const float* W_hh      = (const float*)d_in[10];
    const float* b_hh      = (const float*)d_in[11];
    const float* proj_w    = (const float*)d_in[12];
    const float* proj_b    = (const float*)d_in[13];
    float* out = (float*)d_out;

    char* base = (char*)d_ws;
    size_t off = 0;
    auto alloc = [&](size_t bytes) {
        size_t o = off;
        off = (off + bytes + 255) & ~(size_t)255;
        return o;
    };
    size_t oE2   = alloc((size_t)NVOC * GDIM * 4);       // 158 KB
    size_t oPhi  = alloc((size_t)HIDD * KEYD * 4);       // 154 KB
    size_t oWtb  = alloc((size_t)KPAD * GDIM * 2);       // 1.04 MB
    size_t small_total = off;
    size_t oKbf  = alloc((size_t)SS * BB * KEYD * 2);    // 33.6 MB
    size_t oVbf  = alloc((size_t)SS * BB * VALD * 2);    // 33.6 MB
    size_t full_total = off;

    float* E2 = (float*)(base + oE2);
    float* phi_wT = (float*)(base + oPhi);
    unsigned short* Wtb = (unsigned short*)(base + oWtb);
    unsigned short* kbf = (unsigned short*)(base + oKbf);
    unsigned short* vbf = (unsigned short*)(base + oVbf);

    const bool kvbf = (ws_size >= full_total);
    (void)small_total;

    p_e2<<<NVOC, 256, 0, stream>>>(embedding, W_ih, b_ih, b_hh, E2);
    p_wt<<<2048, 256, 0, stream>>>(W_ih, W_hh, phi_w, Wtb, phi_wT);

    if (kvbf) {
        p_kv<<<(SS * BB * KEYD) / 1024, 1024, 0, stream>>>(keys, values, kbf, vbf);
        decoder_bf<<<NBLK, 1024, 0, stream>>>(
            input, keys, values, kbf, vbf, phi_b, h0, c0,
            proj_w, proj_b, E2, Wtb, phi_wT, out);
    } else {
        decoder_f32<<<NBLK, 1024, 0, stream>>>(
            input, keys, values, (const unsigned short*)nullptr,
            (const unsigned short*)nullptr, phi_b, h0, c0,
            proj_w, proj_b, E2, Wtb, phi_wT, out);
    }
}